// Round 10
// baseline (3179.948 us; speedup 1.0000x reference)
//
#include <hip/hip_runtime.h>

// Inputs: fp32. Outputs: fp32 (established round 3: PASSED).

constexpr int BB = 4;
constexpr int NN = 4096;
constexpr int M1 = 2048;
constexpr int M2 = 512;

typedef float v2f __attribute__((ext_vector_type(2)));

// Exact fp32 squared distance matching numpy's (dx*dx) + (dy*dy), no fma contraction.
__device__ __forceinline__ float d2_exact(float dx, float dy) {
    return __fadd_rn(__fmul_rn(dx, dx), __fmul_rn(dy, dy));
}

// DPP move (old = own value => invalid-source lanes keep themselves; idempotent
// under max). VALU-speed vs ~30-50 cyc ds_permute (measured R3->R4).
template<int CTRL>
__device__ __forceinline__ unsigned dppu(unsigned v) {
    return (unsigned)__builtin_amdgcn_update_dpp((int)v, (int)v, CTRL, 0xF, 0xF, false);
}
template<int CTRL>
__device__ __forceinline__ float dppf(float v) {
    return __uint_as_float(dppu<CTRL>(__float_as_uint(v)));
}
// u64 (hi,lo) max-combine stage.
template<int CTRL>
__device__ __forceinline__ void dppc2(unsigned& hi, unsigned& lo) {
    unsigned ohi = dppu<CTRL>(hi), olo = dppu<CTRL>(lo);
    bool t = (ohi > hi) || (ohi == hi && olo > lo);
    hi = t ? ohi : hi;  lo = t ? olo : lo;
}
__device__ __forceinline__ void ladder64(unsigned& hi, unsigned& lo) {
    dppc2<0x111>(hi, lo); dppc2<0x112>(hi, lo); dppc2<0x114>(hi, lo);
    dppc2<0x118>(hi, lo); dppc2<0x142>(hi, lo); dppc2<0x143>(hi, lo);
}
__device__ __forceinline__ float wave_fmax(float v) {
    v = fmaxf(v, dppf<0x111>(v)); v = fmaxf(v, dppf<0x112>(v));
    v = fmaxf(v, dppf<0x114>(v)); v = fmaxf(v, dppf<0x118>(v));
    v = fmaxf(v, dppf<0x142>(v)); v = fmaxf(v, dppf<0x143>(v));
    return v;   // valid in lane 63
}

// ---------------------------------------------------------------------------
// lf = tanh(tanh(x@W1+b1)@W2+b2) -> out (fp32); also
// y1[j,f] = lf_j@c1W[0:64] + zones_j*c1W[64] + pos_j@c1W[65:67] + c1b (fp32 ws)
// ---------------------------------------------------------------------------
__global__ __launch_bounds__(256) void k_lf_y1(
    const float2* __restrict__ x, const float* __restrict__ zones,
    const float* __restrict__ W1, const float* __restrict__ b1,
    const float* __restrict__ W2, const float* __restrict__ b2,
    const float* __restrict__ c1W, const float* __restrict__ c1b,
    float* __restrict__ out_lf, float* __restrict__ y1)
{
    __shared__ float sh[4][64];
    __shared__ float sl[4][64];
    int tid = threadIdx.x;
    int p = tid >> 6, f = tid & 63;
    size_t pt = (size_t)blockIdx.x * 4 + p;
    float2 xv = x[pt];
    float hid = tanhf(xv.x * W1[f] + xv.y * W1[64 + f] + b1[f]);
    sh[p][f] = hid;
    __syncthreads();
    float acc = b2[f];
#pragma unroll
    for (int c = 0; c < 64; ++c) acc += sh[p][c] * W2[c * 64 + f];
    float lf = tanhf(acc);
    sl[p][f] = lf;
    out_lf[pt * 64 + f] = lf;
    __syncthreads();
    float acc2 = c1b[f] + zones[pt] * c1W[64 * 64 + f]
               + xv.x * c1W[65 * 64 + f] + xv.y * c1W[66 * 64 + f];
#pragma unroll
    for (int c = 0; c < 64; ++c) acc2 += sl[p][c] * c1W[c * 64 + f];
    y1[pt * 64 + f] = acc2;
}

// ---------------------------------------------------------------------------
// SINGLE-WAVE farthest point sampling — bit-exact vs reference scan:
//   md[j] = fmin(md[j], d2_exact(j, c_last)); argmax with FIRST-index
//   tie-break (u64 key = bits(md)<<32 | (0xFFFFFFFF - j)).
// Rationale (R3-R9 post-mortems): per-iter time was pinned ~730-810 ns across
// six multi-wave reduction structures while VALU work varied 3x — the floor is
// the multi-wave barrier + cross-wave LDS round-trips, which the winner wave
// can never skip. One wave per batch removes barriers/atomics/cross-wave LDS
// entirely; in-wave DPP ladders + readlane do the whole argmax.
// Exactness: fp contract OFF in this function (d2 = mul,mul,add rn — matches
// numpy); min/max are IEEE; slot scan descending => smallest q (= smallest j
// within lane) wins equality; cross-lane u64 ladder picks global smallest j
// among max-md holders. j = lane + 64*q.
// ---------------------------------------------------------------------------
template<int NP, int M>
__global__ __launch_bounds__(64, 1) void k_fps(const float2* __restrict__ pos,
                                               float* __restrict__ ctr)
{
#pragma clang fp contract(off)
    constexpr int PPT = NP / 64;          // slots (points) per lane
    constexpr int PP2 = PPT / 2;          // float2 pairs per lane
    __shared__ float2 PTS[NP];            // winner-deref broadcast source
    __shared__ float2 cent[M];
    int lane = threadIdx.x;
    const float2* p = pos + (size_t)blockIdx.x * NP;

    v2f px[PP2], py[PP2], md[PP2];
#pragma unroll
    for (int k = 0; k < PP2; ++k) {
        float2 a = p[lane + 64 * (2 * k)];
        float2 b = p[lane + 64 * (2 * k + 1)];
        px[k] = (v2f){a.x, b.x};
        py[k] = (v2f){a.y, b.y};
        md[k] = (v2f){1e10f, 1e10f};
        PTS[lane + 64 * (2 * k)] = a;
        PTS[lane + 64 * (2 * k + 1)] = b;
    }
    float2 c0 = p[0];
    float cx = c0.x, cy = c0.y;
    if (lane == 0) cent[0] = c0;

    for (int it = 1; it < M; ++it) {
        // ---- phase A: md update + per-lane value max (pairwise, pk-friendly)
        v2f vcx = (v2f){cx, cx}, vcy = (v2f){cy, cy};
        v2f bm2 = (v2f){-1.0f, -1.0f};
#pragma unroll
        for (int k = 0; k < PP2; ++k) {
            v2f dx = px[k] - vcx;
            v2f dy = py[k] - vcy;
            v2f d2 = (dx * dx) + (dy * dy);          // contract off => exact
            md[k] = __builtin_elementwise_min(md[k], d2);
            bm2 = __builtin_elementwise_max(bm2, md[k]);
        }
        float bm = fmaxf(bm2.x, bm2.y);
        // ---- block (=wave) max value, broadcast via readlane
        unsigned bmaxu = (unsigned)__builtin_amdgcn_readlane(
            (int)__float_as_uint(wave_fmax(bm)), 63);
        // ---- phase B: lane-local first-index among md == blockmax
        unsigned bq = 0u;
#pragma unroll
        for (int q = PPT - 1; q >= 0; --q) {         // descending: last write = min q
            float mq = (q & 1) ? md[q >> 1].y : md[q >> 1].x;
            bq = (__float_as_uint(mq) == bmaxu) ? (unsigned)q : bq;
        }
        unsigned hi = __float_as_uint(bm);           // lanes below max lose on hi
        unsigned lo = 0xFFFFFFFFu - ((unsigned)lane + (bq << 6));   // ~j
        ladder64(hi, lo);
        unsigned wlo = (unsigned)__builtin_amdgcn_readlane((int)lo, 63);
        int j = (int)(0xFFFFFFFFu - wlo);
        float2 c = PTS[j];                           // broadcast LDS read
        cx = c.x; cy = c.y;
        if (lane == 0) cent[it] = c;
    }
    float2* co = (float2*)(ctr + (size_t)blockIdx.x * M * 2);
    for (int i = lane; i < M; i += 64) co[i] = cent[i];
}

// ---------------------------------------------------------------------------
// Set abstraction: h[i,f] = max_{j: d2(j,i)<=r2} y[j,f]  -  ctr_i @ W_rel.
// ---------------------------------------------------------------------------
__global__ __launch_bounds__(256) void k_sa(
    const float2* __restrict__ candpos, const float* __restrict__ y,
    const float* __restrict__ ctr, const float* __restrict__ W,
    int NP, int F, int relrow, float r2, float* __restrict__ hout)
{
    __shared__ int cnt;
    __shared__ int list[4096];
    int tid = threadIdx.x;
    int b = blockIdx.y;
    size_t crow = (size_t)b * gridDim.x + blockIdx.x;
    if (tid == 0) cnt = 0;
    __syncthreads();
    float cx = ctr[crow * 2], cy = ctr[crow * 2 + 1];
    const float2* cp = candpos + (size_t)b * NP;
    for (int j = tid; j < NP; j += 256) {
        float2 pj = cp[j];
        float d2 = d2_exact(pj.x - cx, pj.y - cy);
        if (d2 <= r2) { int t = atomicAdd(&cnt, 1); list[t] = j; }
    }
    __syncthreads();
    int n = cnt;
    for (int f = tid; f < F; f += 256) {
        float m = -3.0e38f;
        for (int t = 0; t < n; ++t)
            m = fmaxf(m, y[((size_t)b * NP + list[t]) * F + f]);
        float ct = cx * W[(size_t)relrow * F + f] + cy * W[(size_t)(relrow + 1) * F + f];
        hout[crow * F + f] = m - ct;
    }
}

// ---------------------------------------------------------------------------
// y2[j,f] = h1_j @ c2W[0:64] + pos_j @ c2W[64:66] + c2b
// ---------------------------------------------------------------------------
__global__ __launch_bounds__(128) void k_y2(
    const float* __restrict__ h1, const float* __restrict__ p1,
    const float* __restrict__ W, const float* __restrict__ bb,
    float* __restrict__ y2)
{
    __shared__ float sh[64];
    size_t row = blockIdx.x;
    int f = threadIdx.x;
    if (f < 64) sh[f] = h1[row * 64 + f];
    __syncthreads();
    float acc = bb[f] + p1[row * 2] * W[64 * 128 + f]
              + p1[row * 2 + 1] * W[65 * 128 + f];
#pragma unroll
    for (int c = 0; c < 64; ++c) acc += sh[c] * W[c * 128 + f];
    y2[row * 128 + f] = acc;
}

// ---------------------------------------------------------------------------
// g[i,f] = [h2_i, pos_i] @ c3W + c3b; partial max over 8 rows/thread.
// ---------------------------------------------------------------------------
__global__ __launch_bounds__(256) void k_g(
    const float* __restrict__ h2, const float* __restrict__ p2,
    const float* __restrict__ W3, const float* __restrict__ b3,
    float* __restrict__ part)
{
    int f = blockIdx.x * 256 + threadIdx.x;
    int b = blockIdx.z;
    int i0 = blockIdx.y * 8;
    float acc[8];
    float bbv = b3[f];
#pragma unroll
    for (int ii = 0; ii < 8; ++ii) acc[ii] = bbv;
    const float* hrow = h2 + ((size_t)b * M2 + i0) * 128;
    for (int c = 0; c < 128; ++c) {
        float w = W3[(size_t)c * 1024 + f];
#pragma unroll
        for (int ii = 0; ii < 8; ++ii) acc[ii] += hrow[ii * 128 + c] * w;
    }
    float wx = W3[(size_t)128 * 1024 + f];
    float wy = W3[(size_t)129 * 1024 + f];
    const float* prow = p2 + ((size_t)b * M2 + i0) * 2;
    float m = -3.0e38f;
#pragma unroll
    for (int ii = 0; ii < 8; ++ii) {
        float g = acc[ii] + prow[ii * 2] * wx + prow[ii * 2 + 1] * wy;
        m = fmaxf(m, g);
    }
    part[((size_t)b * 64 + blockIdx.y) * 1024 + f] = m;
}

__global__ __launch_bounds__(256) void k_gmax(const float* __restrict__ part,
                                              float* __restrict__ outg)
{
    int f = blockIdx.x * 256 + threadIdx.x;   // 0..4095
    int b = f >> 10, fl = f & 1023;
    float m = -3.0e38f;
#pragma unroll 8
    for (int ig = 0; ig < 64; ++ig)
        m = fmaxf(m, part[((size_t)b * 64 + ig) * 1024 + fl]);
    outg[f] = m;
}

extern "C" void kernel_launch(void* const* d_in, const int* in_sizes, int n_in,
                              void* d_out, int out_size, void* d_ws, size_t ws_size,
                              hipStream_t stream)
{
    const float* x    = (const float*)d_in[0];
    const float* zon  = (const float*)d_in[1];
    const float* lfW1 = (const float*)d_in[2];
    const float* lfb1 = (const float*)d_in[3];
    const float* lfW2 = (const float*)d_in[4];
    const float* lfb2 = (const float*)d_in[5];
    const float* c1W  = (const float*)d_in[6];
    const float* c1b  = (const float*)d_in[7];
    const float* c2W  = (const float*)d_in[8];
    const float* c2b  = (const float*)d_in[9];
    const float* c3W  = (const float*)d_in[10];
    const float* c3b  = (const float*)d_in[11];
    float* out = (float*)d_out;

    // Workspace (fp32). "big" (4 MB) reused: y1 -> y2 -> part.
    char* w = (char*)d_ws;
    float* big = (float*)w;                    w += (size_t)BB * NN * 64 * 4;   // 4 MB
    float* p1  = (float*)w;                    w += (size_t)BB * M1 * 2 * 4;
    float* h1  = (float*)w;                    w += (size_t)BB * M1 * 64 * 4;   // 2 MB
    float* p2  = (float*)w;                    w += (size_t)BB * M2 * 2 * 4;
    float* h2  = (float*)w;                    w += (size_t)BB * M2 * 128 * 4;  // 1 MB
    float* y1 = big, * y2 = big, * part = big;

    k_lf_y1<<<BB * NN / 4, 256, 0, stream>>>((const float2*)x, zon, lfW1, lfb1,
                                             lfW2, lfb2, c1W, c1b, out, y1);
    k_fps<NN, M1><<<BB, 64, 0, stream>>>((const float2*)x, p1);
    k_sa<<<dim3(M1, BB), 256, 0, stream>>>((const float2*)x, y1, p1, c1W,
                                           NN, 64, 65, 0.25f, h1);
    k_fps<M1, M2><<<BB, 64, 0, stream>>>((const float2*)p1, p2);
    k_y2<<<BB * M1, 128, 0, stream>>>(h1, p1, c2W, c2b, y2);
    k_sa<<<dim3(M2, BB), 256, 0, stream>>>((const float2*)p1, y2, p2, c2W,
                                           M1, 128, 64, 1.0f, h2);
    k_g<<<dim3(4, 64, BB), 256, 0, stream>>>(h2, p2, c3W, c3b, part);
    k_gmax<<<16, 256, 0, stream>>>(part, out + (size_t)BB * NN * 64);
}

// Round 11
// 1711.653 us; speedup vs baseline: 1.8578x; 1.8578x over previous
//
#include <hip/hip_runtime.h>

// Inputs: fp32. Outputs: fp32 (established round 3: PASSED).

constexpr int BB = 4;
constexpr int NN = 4096;
constexpr int M1 = 2048;
constexpr int M2 = 512;

// Exact fp32 squared distance matching numpy's (dx*dx) + (dy*dy), no fma contraction.
__device__ __forceinline__ float d2_exact(float dx, float dy) {
    return __fadd_rn(__fmul_rn(dx, dx), __fmul_rn(dy, dy));
}

// DPP with bound_ctrl=1 (invalid source lanes read 0). Zero pairs lose all
// combines (keys > 0 always), so the top-2 pair ladder never double-counts a
// lane's own pair (which old=own DPP would do, corrupting the runner-up).
template<int CTRL>
__device__ __forceinline__ unsigned long long dpp64z(unsigned long long v) {
    unsigned lo = (unsigned)__builtin_amdgcn_update_dpp(0, (int)(unsigned)v, CTRL, 0xF, 0xF, true);
    unsigned hi = (unsigned)__builtin_amdgcn_update_dpp(0, (int)(unsigned)(v >> 32), CTRL, 0xF, 0xF, true);
    return ((unsigned long long)hi << 32) | (unsigned long long)lo;
}
// (top1, top2) pair combine with CTRL-selected partner pair. Keys unique.
template<int CTRL>
__device__ __forceinline__ void pairc(unsigned long long& t1, unsigned long long& t2) {
    unsigned long long o1 = dpp64z<CTRL>(t1);
    unsigned long long o2 = dpp64z<CTRL>(t2);
    bool g = o1 > t1;
    unsigned long long m1 = g ? o1 : t1;
    unsigned long long sm = g ? t1 : o1;
    unsigned long long cn = g ? o2 : t2;
    t2 = cn > sm ? cn : sm;
    t1 = m1;
}
__device__ __forceinline__ unsigned long long readlane64(unsigned long long v, int l) {
    unsigned lo = (unsigned)__builtin_amdgcn_readlane((int)(unsigned)v, l);
    unsigned hi = (unsigned)__builtin_amdgcn_readlane((int)(unsigned)(v >> 32), l);
    return ((unsigned long long)hi << 32) | (unsigned long long)lo;
}

// ---------------------------------------------------------------------------
// lf = tanh(tanh(x@W1+b1)@W2+b2) -> out (fp32); also
// y1[j,f] = lf_j@c1W[0:64] + zones_j*c1W[64] + pos_j@c1W[65:67] + c1b (fp32 ws)
// ---------------------------------------------------------------------------
__global__ __launch_bounds__(256) void k_lf_y1(
    const float2* __restrict__ x, const float* __restrict__ zones,
    const float* __restrict__ W1, const float* __restrict__ b1,
    const float* __restrict__ W2, const float* __restrict__ b2,
    const float* __restrict__ c1W, const float* __restrict__ c1b,
    float* __restrict__ out_lf, float* __restrict__ y1)
{
    __shared__ float sh[4][64];
    __shared__ float sl[4][64];
    int tid = threadIdx.x;
    int p = tid >> 6, f = tid & 63;
    size_t pt = (size_t)blockIdx.x * 4 + p;
    float2 xv = x[pt];
    float hid = tanhf(xv.x * W1[f] + xv.y * W1[64 + f] + b1[f]);
    sh[p][f] = hid;
    __syncthreads();
    float acc = b2[f];
#pragma unroll
    for (int c = 0; c < 64; ++c) acc += sh[p][c] * W2[c * 64 + f];
    float lf = tanhf(acc);
    sl[p][f] = lf;
    out_lf[pt * 64 + f] = lf;
    __syncthreads();
    float acc2 = c1b[f] + zones[pt] * c1W[64 * 64 + f]
               + xv.x * c1W[65 * 64 + f] + xv.y * c1W[66 * 64 + f];
#pragma unroll
    for (int c = 0; c < 64; ++c) acc2 += sl[p][c] * c1W[c * 64 + f];
    y1[pt * 64 + f] = acc2;
}

// ---------------------------------------------------------------------------
// FPS with exact top-2 speculation — bit-exact vs the reference scan:
//   md[j] = fmin(md[j], d2_exact(j, c)); argmax w/ FIRST-index tie-break via
//   unique u64 key = bits(md)<<32 | (0xFFFFFFFF - j).
// Per round, reduce (top1, top2) keys. If d2_exact(r1, w1) >= md_r1 then the
// NEXT reference pick is exactly r1 (proof: all other keys were < key_r1 and
// updates only lower md; equal-md cases resolve by ~j identically), so two
// centers are emitted per round — cutting the serial round count, which
// R3-R10 showed is the only lever (per-round floor ~700 ns is structural).
// 8 waves x PPT slots; one barrier/round; parity-double-buffered slot pairs.
// No global memory ops inside the loop.
// ---------------------------------------------------------------------------
template<int NP, int M>
__global__ __launch_bounds__(512) void k_fps(const float2* __restrict__ pos,
                                             float* __restrict__ ctr)
{
#pragma clang fp contract(off)
    constexpr int PPT = NP / 512;
    __shared__ float2 PTS[NP];            // original order, winner deref source
    __shared__ float2 cent[M];
    __shared__ unsigned long long sl[2][16];   // [parity][wave*2 + {top1,top2}]
    int tid = threadIdx.x, lane = tid & 63, wv = tid >> 6;
    const float2* p = pos + (size_t)blockIdx.x * NP;

    float px[PPT], py[PPT], md[PPT];
    unsigned lowk[PPT];
#pragma unroll
    for (int s = 0; s < PPT; ++s) {
        float2 v = p[tid + s * 512];
        px[s] = v.x; py[s] = v.y; md[s] = 1e10f;
        lowk[s] = 0xFFFFFFFFu - (unsigned)(tid + s * 512);
        PTS[tid + s * 512] = v;
    }
    float2 c0 = p[0];
    if (tid == 0) cent[0] = c0;
    __syncthreads();

    float c1x = c0.x, c1y = c0.y, c2x = 0.0f, c2y = 0.0f;
    bool two = false;
    int it = 1;
    unsigned rc = 0;
    while (it < M) {
        int par = (int)(rc & 1u); ++rc;
        // ---- update md by pending center(s) ----
#pragma unroll
        for (int s = 0; s < PPT; ++s)
            md[s] = fminf(md[s], d2_exact(px[s] - c1x, py[s] - c1y));
        if (two) {
#pragma unroll
            for (int s = 0; s < PPT; ++s)
                md[s] = fminf(md[s], d2_exact(px[s] - c2x, py[s] - c2y));
        }
        // ---- per-lane top-2 keys ----
        unsigned long long t1 = 0ull, t2 = 0ull;
#pragma unroll
        for (int s = 0; s < PPT; ++s) {
            unsigned long long key =
                ((unsigned long long)__float_as_uint(md[s]) << 32) | (unsigned long long)lowk[s];
            bool g = key > t1;
            unsigned long long ns = g ? t1 : (key > t2 ? key : t2);
            t1 = g ? key : t1;
            t2 = ns;
        }
        // ---- wave pair ladder -> lane 63 ----
        pairc<0x111>(t1, t2); pairc<0x112>(t1, t2); pairc<0x114>(t1, t2);
        pairc<0x118>(t1, t2); pairc<0x142>(t1, t2); pairc<0x143>(t1, t2);
        if (lane == 63) { sl[par][2 * wv] = t1; sl[par][2 * wv + 1] = t2; }
        __syncthreads();                   // the only barrier per round
        // ---- cross-wave pair tree over 8 slots (lanes 0-7 hold pairs) ----
        unsigned long long a1 = sl[par][2 * (lane & 7)];
        unsigned long long a2 = sl[par][2 * (lane & 7) + 1];
        if (lane >= 8) { a1 = 0ull; a2 = 0ull; }
        pairc<0x111>(a1, a2); pairc<0x112>(a1, a2); pairc<0x114>(a1, a2);
        unsigned long long w1 = readlane64(a1, 7);
        unsigned long long r1 = readlane64(a2, 7);
        int jw = (int)(0xFFFFFFFFu - (unsigned)w1);
        int jr = (int)(0xFFFFFFFFu - (unsigned)r1);
        float mdr = __uint_as_float((unsigned)(r1 >> 32));
        float2 wpt = PTS[jw];              // broadcast LDS reads (independent)
        float2 rpt = PTS[jr];
        float ddx = rpt.x - wpt.x, ddy = rpt.y - wpt.y;
        float dd = (ddx * ddx) + (ddy * ddy);    // contract off => exact rn
        bool dbl = (it + 1 < M) && (dd >= mdr);  // uniform
        if (tid == 0) { cent[it] = wpt; if (dbl) cent[it + 1] = rpt; }
        c1x = wpt.x; c1y = wpt.y; c2x = rpt.x; c2y = rpt.y;
        two = dbl;
        it += dbl ? 2 : 1;
    }
    __syncthreads();
    float2* co = (float2*)(ctr + (size_t)blockIdx.x * M * 2);
    for (int i = tid; i < M; i += 512) co[i] = cent[i];
}

// ---------------------------------------------------------------------------
// Set abstraction: h[i,f] = max_{j: d2(j,i)<=r2} y[j,f]  -  ctr_i @ W_rel.
// ---------------------------------------------------------------------------
__global__ __launch_bounds__(256) void k_sa(
    const float2* __restrict__ candpos, const float* __restrict__ y,
    const float* __restrict__ ctr, const float* __restrict__ W,
    int NP, int F, int relrow, float r2, float* __restrict__ hout)
{
    __shared__ int cnt;
    __shared__ int list[4096];
    int tid = threadIdx.x;
    int b = blockIdx.y;
    size_t crow = (size_t)b * gridDim.x + blockIdx.x;
    if (tid == 0) cnt = 0;
    __syncthreads();
    float cx = ctr[crow * 2], cy = ctr[crow * 2 + 1];
    const float2* cp = candpos + (size_t)b * NP;
    for (int j = tid; j < NP; j += 256) {
        float2 pj = cp[j];
        float d2 = d2_exact(pj.x - cx, pj.y - cy);
        if (d2 <= r2) { int t = atomicAdd(&cnt, 1); list[t] = j; }
    }
    __syncthreads();
    int n = cnt;
    for (int f = tid; f < F; f += 256) {
        float m = -3.0e38f;
        for (int t = 0; t < n; ++t)
            m = fmaxf(m, y[((size_t)b * NP + list[t]) * F + f]);
        float ct = cx * W[(size_t)relrow * F + f] + cy * W[(size_t)(relrow + 1) * F + f];
        hout[crow * F + f] = m - ct;
    }
}

// ---------------------------------------------------------------------------
// y2[j,f] = h1_j @ c2W[0:64] + pos_j @ c2W[64:66] + c2b
// ---------------------------------------------------------------------------
__global__ __launch_bounds__(128) void k_y2(
    const float* __restrict__ h1, const float* __restrict__ p1,
    const float* __restrict__ W, const float* __restrict__ bb,
    float* __restrict__ y2)
{
    __shared__ float sh[64];
    size_t row = blockIdx.x;
    int f = threadIdx.x;
    if (f < 64) sh[f] = h1[row * 64 + f];
    __syncthreads();
    float acc = bb[f] + p1[row * 2] * W[64 * 128 + f]
              + p1[row * 2 + 1] * W[65 * 128 + f];
#pragma unroll
    for (int c = 0; c < 64; ++c) acc += sh[c] * W[c * 128 + f];
    y2[row * 128 + f] = acc;
}

// ---------------------------------------------------------------------------
// g[i,f] = [h2_i, pos_i] @ c3W + c3b; partial max over 8 rows/thread.
// ---------------------------------------------------------------------------
__global__ __launch_bounds__(256) void k_g(
    const float* __restrict__ h2, const float* __restrict__ p2,
    const float* __restrict__ W3, const float* __restrict__ b3,
    float* __restrict__ part)
{
    int f = blockIdx.x * 256 + threadIdx.x;
    int b = blockIdx.z;
    int i0 = blockIdx.y * 8;
    float acc[8];
    float bbv = b3[f];
#pragma unroll
    for (int ii = 0; ii < 8; ++ii) acc[ii] = bbv;
    const float* hrow = h2 + ((size_t)b * M2 + i0) * 128;
    for (int c = 0; c < 128; ++c) {
        float w = W3[(size_t)c * 1024 + f];
#pragma unroll
        for (int ii = 0; ii < 8; ++ii) acc[ii] += hrow[ii * 128 + c] * w;
    }
    float wx = W3[(size_t)128 * 1024 + f];
    float wy = W3[(size_t)129 * 1024 + f];
    const float* prow = p2 + ((size_t)b * M2 + i0) * 2;
    float m = -3.0e38f;
#pragma unroll
    for (int ii = 0; ii < 8; ++ii) {
        float g = acc[ii] + prow[ii * 2] * wx + prow[ii * 2 + 1] * wy;
        m = fmaxf(m, g);
    }
    part[((size_t)b * 64 + blockIdx.y) * 1024 + f] = m;
}

__global__ __launch_bounds__(256) void k_gmax(const float* __restrict__ part,
                                              float* __restrict__ outg)
{
    int f = blockIdx.x * 256 + threadIdx.x;   // 0..4095
    int b = f >> 10, fl = f & 1023;
    float m = -3.0e38f;
#pragma unroll 8
    for (int ig = 0; ig < 64; ++ig)
        m = fmaxf(m, part[((size_t)b * 64 + ig) * 1024 + fl]);
    outg[f] = m;
}

extern "C" void kernel_launch(void* const* d_in, const int* in_sizes, int n_in,
                              void* d_out, int out_size, void* d_ws, size_t ws_size,
                              hipStream_t stream)
{
    const float* x    = (const float*)d_in[0];
    const float* zon  = (const float*)d_in[1];
    const float* lfW1 = (const float*)d_in[2];
    const float* lfb1 = (const float*)d_in[3];
    const float* lfW2 = (const float*)d_in[4];
    const float* lfb2 = (const float*)d_in[5];
    const float* c1W  = (const float*)d_in[6];
    const float* c1b  = (const float*)d_in[7];
    const float* c2W  = (const float*)d_in[8];
    const float* c2b  = (const float*)d_in[9];
    const float* c3W  = (const float*)d_in[10];
    const float* c3b  = (const float*)d_in[11];
    float* out = (float*)d_out;

    // Workspace (fp32). "big" (4 MB) reused: y1 -> y2 -> part.
    char* w = (char*)d_ws;
    float* big = (float*)w;                    w += (size_t)BB * NN * 64 * 4;   // 4 MB
    float* p1  = (float*)w;                    w += (size_t)BB * M1 * 2 * 4;
    float* h1  = (float*)w;                    w += (size_t)BB * M1 * 64 * 4;   // 2 MB
    float* p2  = (float*)w;                    w += (size_t)BB * M2 * 2 * 4;
    float* h2  = (float*)w;                    w += (size_t)BB * M2 * 128 * 4;  // 1 MB
    float* y1 = big, * y2 = big, * part = big;

    k_lf_y1<<<BB * NN / 4, 256, 0, stream>>>((const float2*)x, zon, lfW1, lfb1,
                                             lfW2, lfb2, c1W, c1b, out, y1);
    k_fps<NN, M1><<<BB, 512, 0, stream>>>((const float2*)x, p1);
    k_sa<<<dim3(M1, BB), 256, 0, stream>>>((const float2*)x, y1, p1, c1W,
                                           NN, 64, 65, 0.25f, h1);
    k_fps<M1, M2><<<BB, 512, 0, stream>>>((const float2*)p1, p2);
    k_y2<<<BB * M1, 128, 0, stream>>>(h1, p1, c2W, c2b, y2);
    k_sa<<<dim3(M2, BB), 256, 0, stream>>>((const float2*)p1, y2, p2, c2W,
                                           M1, 128, 64, 1.0f, h2);
    k_g<<<dim3(4, 64, BB), 256, 0, stream>>>(h2, p2, c3W, c3b, part);
    k_gmax<<<16, 256, 0, stream>>>(part, out + (size_t)BB * NN * 64);
}

// Round 12
// 1684.313 us; speedup vs baseline: 1.8880x; 1.0162x over previous
//
#include <hip/hip_runtime.h>

// Inputs: fp32. Outputs: fp32 (established round 3: PASSED).

constexpr int BB = 4;
constexpr int NN = 4096;
constexpr int M1 = 2048;
constexpr int M2 = 512;

typedef float v2f __attribute__((ext_vector_type(2)));

// Exact fp32 squared distance matching numpy's (dx*dx) + (dy*dy), no fma contraction.
__device__ __forceinline__ float d2_exact(float dx, float dy) {
    return __fadd_rn(__fmul_rn(dx, dx), __fmul_rn(dy, dy));
}

// DPP with bound_ctrl=1 (invalid source lanes read 0). Zero pairs lose all
// combines (real keys > 0), so the top-2 pair ladder never double-counts a
// lane's own pair.
template<int CTRL>
__device__ __forceinline__ unsigned long long dpp64z(unsigned long long v) {
    unsigned lo = (unsigned)__builtin_amdgcn_update_dpp(0, (int)(unsigned)v, CTRL, 0xF, 0xF, true);
    unsigned hi = (unsigned)__builtin_amdgcn_update_dpp(0, (int)(unsigned)(v >> 32), CTRL, 0xF, 0xF, true);
    return ((unsigned long long)hi << 32) | (unsigned long long)lo;
}
// (top1, top2) pair combine with CTRL-selected partner pair. Keys unique.
template<int CTRL>
__device__ __forceinline__ void pairc(unsigned long long& t1, unsigned long long& t2) {
    unsigned long long o1 = dpp64z<CTRL>(t1);
    unsigned long long o2 = dpp64z<CTRL>(t2);
    bool g = o1 > t1;
    unsigned long long m1 = g ? o1 : t1;
    unsigned long long sm = g ? t1 : o1;
    unsigned long long cn = g ? o2 : t2;
    t2 = cn > sm ? cn : sm;
    t1 = m1;
}
__device__ __forceinline__ unsigned long long readlane64(unsigned long long v, int l) {
    unsigned lo = (unsigned)__builtin_amdgcn_readlane((int)(unsigned)v, l);
    unsigned hi = (unsigned)__builtin_amdgcn_readlane((int)(unsigned)(v >> 32), l);
    return ((unsigned long long)hi << 32) | (unsigned long long)lo;
}

// ---------------------------------------------------------------------------
// lf = tanh(tanh(x@W1+b1)@W2+b2) -> out (fp32); also
// y1[j,f] = lf_j@c1W[0:64] + zones_j*c1W[64] + pos_j@c1W[65:67] + c1b (fp32 ws)
// ---------------------------------------------------------------------------
__global__ __launch_bounds__(256) void k_lf_y1(
    const float2* __restrict__ x, const float* __restrict__ zones,
    const float* __restrict__ W1, const float* __restrict__ b1,
    const float* __restrict__ W2, const float* __restrict__ b2,
    const float* __restrict__ c1W, const float* __restrict__ c1b,
    float* __restrict__ out_lf, float* __restrict__ y1)
{
    __shared__ float sh[4][64];
    __shared__ float sl[4][64];
    int tid = threadIdx.x;
    int p = tid >> 6, f = tid & 63;
    size_t pt = (size_t)blockIdx.x * 4 + p;
    float2 xv = x[pt];
    float hid = tanhf(xv.x * W1[f] + xv.y * W1[64 + f] + b1[f]);
    sh[p][f] = hid;
    __syncthreads();
    float acc = b2[f];
#pragma unroll
    for (int c = 0; c < 64; ++c) acc += sh[p][c] * W2[c * 64 + f];
    float lf = tanhf(acc);
    sl[p][f] = lf;
    out_lf[pt * 64 + f] = lf;
    __syncthreads();
    float acc2 = c1b[f] + zones[pt] * c1W[64 * 64 + f]
               + xv.x * c1W[65 * 64 + f] + xv.y * c1W[66 * 64 + f];
#pragma unroll
    for (int c = 0; c < 64; ++c) acc2 += sl[p][c] * c1W[c * 64 + f];
    y1[pt * 64 + f] = acc2;
}

// ---------------------------------------------------------------------------
// FPS core with exact top-2 speculation — bit-exact vs the reference scan
// (R11 structure, WIN; + packed v2f update math, bit-exact per R10):
//   md[j] = fmin(md[j], d2_exact(j, c)); argmax w/ FIRST-index tie-break via
//   unique u64 key = bits(md)<<32 | (0xFFFFFFFF - j).
// If d2_exact(r1, w1) >= md_r1 the next reference pick is exactly r1 (all
// other keys < key_r1; updates only lower md; ties resolve by ~j) -> emit 2.
// src: point source (global for stage 1, LDS cent1 for stage 2), original
// order. PTSl: LDS table for winner deref. centl: LDS output.
// Caller must __syncthreads() after PTSl/src(LDS) is complete.
// ---------------------------------------------------------------------------
template<int M, int PPT>
__device__ __forceinline__ void fps_core(
    const float2* __restrict__ src, const float2* __restrict__ PTSl,
    float2* __restrict__ centl, unsigned long long (&sl)[2][16],
    int tid, int lane, int wv)
{
#pragma clang fp contract(off)
    constexpr int PP2 = PPT / 2;
    v2f px2[PP2], py2[PP2], md2[PP2];
#pragma unroll
    for (int k = 0; k < PP2; ++k) {
        float2 a = src[tid + (2 * k) * 512];
        float2 b = src[tid + (2 * k + 1) * 512];
        px2[k] = (v2f){a.x, b.x};
        py2[k] = (v2f){a.y, b.y};
        md2[k] = (v2f){1e10f, 1e10f};
    }
    float2 c0 = src[0];
    if (tid == 0) centl[0] = c0;

    float c1x = c0.x, c1y = c0.y, c2x = 0.0f, c2y = 0.0f;
    bool two = false;
    int it = 1;
    unsigned rc = 0;
    while (it < M) {
        int par = (int)(rc & 1u); ++rc;
        // ---- packed md update by pending center(s); rn per half == scalar rn
        v2f vcx = (v2f){c1x, c1x}, vcy = (v2f){c1y, c1y};
#pragma unroll
        for (int k = 0; k < PP2; ++k) {
            v2f dx = px2[k] - vcx, dy = py2[k] - vcy;
            v2f d2 = (dx * dx) + (dy * dy);          // contract off => exact
            md2[k] = __builtin_elementwise_min(md2[k], d2);
        }
        if (two) {
            v2f wcx = (v2f){c2x, c2x}, wcy = (v2f){c2y, c2y};
#pragma unroll
            for (int k = 0; k < PP2; ++k) {
                v2f dx = px2[k] - wcx, dy = py2[k] - wcy;
                v2f d2 = (dx * dx) + (dy * dy);
                md2[k] = __builtin_elementwise_min(md2[k], d2);
            }
        }
        // ---- per-lane top-2 keys ----
        unsigned long long t1 = 0ull, t2 = 0ull;
#pragma unroll
        for (int s = 0; s < PPT; ++s) {
            float mq = (s & 1) ? md2[s >> 1].y : md2[s >> 1].x;
            unsigned long long key =
                ((unsigned long long)__float_as_uint(mq) << 32)
                | (unsigned long long)(0xFFFFFFFFu - (unsigned)(tid + s * 512));
            bool g = key > t1;
            unsigned long long ns = g ? t1 : (key > t2 ? key : t2);
            t1 = g ? key : t1;
            t2 = ns;
        }
        // ---- wave pair ladder -> lane 63 ----
        pairc<0x111>(t1, t2); pairc<0x112>(t1, t2); pairc<0x114>(t1, t2);
        pairc<0x118>(t1, t2); pairc<0x142>(t1, t2); pairc<0x143>(t1, t2);
        if (lane == 63) { sl[par][2 * wv] = t1; sl[par][2 * wv + 1] = t2; }
        __syncthreads();                   // the only barrier per round
        // ---- cross-wave pair tree over 8 slots ----
        unsigned long long a1 = sl[par][2 * (lane & 7)];
        unsigned long long a2 = sl[par][2 * (lane & 7) + 1];
        if (lane >= 8) { a1 = 0ull; a2 = 0ull; }
        pairc<0x111>(a1, a2); pairc<0x112>(a1, a2); pairc<0x114>(a1, a2);
        unsigned long long w1 = readlane64(a1, 7);
        unsigned long long r1 = readlane64(a2, 7);
        int jw = (int)(0xFFFFFFFFu - (unsigned)w1);
        int jr = (int)(0xFFFFFFFFu - (unsigned)r1);
        float mdr = __uint_as_float((unsigned)(r1 >> 32));
        float2 wpt = PTSl[jw];             // broadcast LDS reads (independent)
        float2 rpt = PTSl[jr];
        float ddx = rpt.x - wpt.x, ddy = rpt.y - wpt.y;
        float dd = (ddx * ddx) + (ddy * ddy);    // contract off => exact rn
        bool dbl = (it + 1 < M) && (dd >= mdr);  // uniform
        if (tid == 0) { centl[it] = wpt; if (dbl) centl[it + 1] = rpt; }
        c1x = wpt.x; c1y = wpt.y; c2x = rpt.x; c2y = rpt.y;
        two = dbl;
        it += dbl ? 2 : 1;
    }
}

// ---------------------------------------------------------------------------
// Fused FPS stage1 (4096 -> 2048 centers) + stage2 (2048 -> 512 centers).
// Stage 2's input IS stage 1's LDS-resident cent1 (selection order = p1
// order), so fusing removes a launch, the global p1 round-trip for stage 2,
// and the sa1-before-fps2 stream serialization.
// ---------------------------------------------------------------------------
__global__ __launch_bounds__(512, 2) void k_fps_fused(
    const float2* __restrict__ pos, float* __restrict__ p1out,
    float* __restrict__ p2out)
{
    __shared__ float2 PTS[NN];            // 32 KB
    __shared__ float2 cent1[M1];          // 16 KB
    __shared__ float2 cent2[M2];          // 4 KB
    __shared__ unsigned long long sl[2][16];
    int tid = threadIdx.x, lane = tid & 63, wv = tid >> 6;
    const float2* p = pos + (size_t)blockIdx.x * NN;

    for (int i = tid; i < NN; i += 512) PTS[i] = p[i];
    __syncthreads();                      // PTS complete

    fps_core<M1, NN / 512>(p, PTS, cent1, sl, tid, lane, wv);
    __syncthreads();                      // cent1 complete
    float2* o1 = (float2*)(p1out + (size_t)blockIdx.x * M1 * 2);
    for (int i = tid; i < M1; i += 512) o1[i] = cent1[i];   // background stores

    fps_core<M2, M1 / 512>(cent1, cent1, cent2, sl, tid, lane, wv);
    __syncthreads();                      // cent2 complete
    float2* o2 = (float2*)(p2out + (size_t)blockIdx.x * M2 * 2);
    for (int i = tid; i < M2; i += 512) o2[i] = cent2[i];
}

// ---------------------------------------------------------------------------
// Set abstraction: h[i,f] = max_{j: d2(j,i)<=r2} y[j,f]  -  ctr_i @ W_rel.
// ---------------------------------------------------------------------------
__global__ __launch_bounds__(256) void k_sa(
    const float2* __restrict__ candpos, const float* __restrict__ y,
    const float* __restrict__ ctr, const float* __restrict__ W,
    int NP, int F, int relrow, float r2, float* __restrict__ hout)
{
    __shared__ int cnt;
    __shared__ int list[4096];
    int tid = threadIdx.x;
    int b = blockIdx.y;
    size_t crow = (size_t)b * gridDim.x + blockIdx.x;
    if (tid == 0) cnt = 0;
    __syncthreads();
    float cx = ctr[crow * 2], cy = ctr[crow * 2 + 1];
    const float2* cp = candpos + (size_t)b * NP;
    for (int j = tid; j < NP; j += 256) {
        float2 pj = cp[j];
        float d2 = d2_exact(pj.x - cx, pj.y - cy);
        if (d2 <= r2) { int t = atomicAdd(&cnt, 1); list[t] = j; }
    }
    __syncthreads();
    int n = cnt;
    for (int f = tid; f < F; f += 256) {
        float m = -3.0e38f;
        for (int t = 0; t < n; ++t)
            m = fmaxf(m, y[((size_t)b * NP + list[t]) * F + f]);
        float ct = cx * W[(size_t)relrow * F + f] + cy * W[(size_t)(relrow + 1) * F + f];
        hout[crow * F + f] = m - ct;
    }
}

// ---------------------------------------------------------------------------
// y2[j,f] = h1_j @ c2W[0:64] + pos_j @ c2W[64:66] + c2b
// ---------------------------------------------------------------------------
__global__ __launch_bounds__(128) void k_y2(
    const float* __restrict__ h1, const float* __restrict__ p1,
    const float* __restrict__ W, const float* __restrict__ bb,
    float* __restrict__ y2)
{
    __shared__ float sh[64];
    size_t row = blockIdx.x;
    int f = threadIdx.x;
    if (f < 64) sh[f] = h1[row * 64 + f];
    __syncthreads();
    float acc = bb[f] + p1[row * 2] * W[64 * 128 + f]
              + p1[row * 2 + 1] * W[65 * 128 + f];
#pragma unroll
    for (int c = 0; c < 64; ++c) acc += sh[c] * W[c * 128 + f];
    y2[row * 128 + f] = acc;
}

// ---------------------------------------------------------------------------
// g[i,f] = [h2_i, pos_i] @ c3W + c3b; partial max over 8 rows/thread.
// ---------------------------------------------------------------------------
__global__ __launch_bounds__(256) void k_g(
    const float* __restrict__ h2, const float* __restrict__ p2,
    const float* __restrict__ W3, const float* __restrict__ b3,
    float* __restrict__ part)
{
    int f = blockIdx.x * 256 + threadIdx.x;
    int b = blockIdx.z;
    int i0 = blockIdx.y * 8;
    float acc[8];
    float bbv = b3[f];
#pragma unroll
    for (int ii = 0; ii < 8; ++ii) acc[ii] = bbv;
    const float* hrow = h2 + ((size_t)b * M2 + i0) * 128;
    for (int c = 0; c < 128; ++c) {
        float w = W3[(size_t)c * 1024 + f];
#pragma unroll
        for (int ii = 0; ii < 8; ++ii) acc[ii] += hrow[ii * 128 + c] * w;
    }
    float wx = W3[(size_t)128 * 1024 + f];
    float wy = W3[(size_t)129 * 1024 + f];
    const float* prow = p2 + ((size_t)b * M2 + i0) * 2;
    float m = -3.0e38f;
#pragma unroll
    for (int ii = 0; ii < 8; ++ii) {
        float g = acc[ii] + prow[ii * 2] * wx + prow[ii * 2 + 1] * wy;
        m = fmaxf(m, g);
    }
    part[((size_t)b * 64 + blockIdx.y) * 1024 + f] = m;
}

__global__ __launch_bounds__(256) void k_gmax(const float* __restrict__ part,
                                              float* __restrict__ outg)
{
    int f = blockIdx.x * 256 + threadIdx.x;   // 0..4095
    int b = f >> 10, fl = f & 1023;
    float m = -3.0e38f;
#pragma unroll 8
    for (int ig = 0; ig < 64; ++ig)
        m = fmaxf(m, part[((size_t)b * 64 + ig) * 1024 + fl]);
    outg[f] = m;
}

extern "C" void kernel_launch(void* const* d_in, const int* in_sizes, int n_in,
                              void* d_out, int out_size, void* d_ws, size_t ws_size,
                              hipStream_t stream)
{
    const float* x    = (const float*)d_in[0];
    const float* zon  = (const float*)d_in[1];
    const float* lfW1 = (const float*)d_in[2];
    const float* lfb1 = (const float*)d_in[3];
    const float* lfW2 = (const float*)d_in[4];
    const float* lfb2 = (const float*)d_in[5];
    const float* c1W  = (const float*)d_in[6];
    const float* c1b  = (const float*)d_in[7];
    const float* c2W  = (const float*)d_in[8];
    const float* c2b  = (const float*)d_in[9];
    const float* c3W  = (const float*)d_in[10];
    const float* c3b  = (const float*)d_in[11];
    float* out = (float*)d_out;

    // Workspace (fp32). "big" (4 MB) reused: y1 -> y2 -> part.
    char* w = (char*)d_ws;
    float* big = (float*)w;                    w += (size_t)BB * NN * 64 * 4;   // 4 MB
    float* p1  = (float*)w;                    w += (size_t)BB * M1 * 2 * 4;
    float* h1  = (float*)w;                    w += (size_t)BB * M1 * 64 * 4;   // 2 MB
    float* p2  = (float*)w;                    w += (size_t)BB * M2 * 2 * 4;
    float* h2  = (float*)w;                    w += (size_t)BB * M2 * 128 * 4;  // 1 MB
    float* y1 = big, * y2 = big, * part = big;

    k_lf_y1<<<BB * NN / 4, 256, 0, stream>>>((const float2*)x, zon, lfW1, lfb1,
                                             lfW2, lfb2, c1W, c1b, out, y1);
    k_fps_fused<<<BB, 512, 0, stream>>>((const float2*)x, p1, p2);
    k_sa<<<dim3(M1, BB), 256, 0, stream>>>((const float2*)x, y1, p1, c1W,
                                           NN, 64, 65, 0.25f, h1);
    k_y2<<<BB * M1, 128, 0, stream>>>(h1, p1, c2W, c2b, y2);
    k_sa<<<dim3(M2, BB), 256, 0, stream>>>((const float2*)p1, y2, p2, c2W,
                                           M1, 128, 64, 1.0f, h2);
    k_g<<<dim3(4, 64, BB), 256, 0, stream>>>(h2, p2, c3W, c3b, part);
    k_gmax<<<16, 256, 0, stream>>>(part, out + (size_t)BB * NN * 64);
}